// Round 20
// baseline (92.143 us; speedup 1.0000x reference)
//
#include <hip/hip_runtime.h>
#include <hip/hip_bf16.h>
#include <cstddef>
#include <cstdint>

// Problem constants (fixed by the reference setup)
#define N_B   8
#define L_L   4096
#define S_S   4096
#define H_H   8
#define D_D   64
#define NH    64          // N_B * H_H
// KV_aug layout (d-major): rows 0..63 = KV[d][v] (stride 68, cols 64..67 pad),
// row 64 = K_sum[d] (indexed by d in cols 0..63). KVSZ floats per (n,h).
#define KVLD  68
#define KVSZ  (65 * KVLD)   // 4420
#define ROWF  (H_H * D_D)   // 512 floats per s-row
#define TSTEP (32 * ROWF)   // floats per 32-s tile step
#define KTLD  40            // bf16 (short) row stride of transposed tiles (80 B)

typedef float f32x4 __attribute__((ext_vector_type(4)));
typedef short bf16x8 __attribute__((ext_vector_type(8)));

__device__ __forceinline__ float elu1(float x) {
    // elu(x)+1 : x>0 ? x+1 : exp(x)
    return x > 0.f ? x + 1.f : __expf(x);
}

// pack (a,b) -> bf16x2 (RNE) and store at transposed position [d][2*a2..+1]
__device__ __forceinline__ void wr_pair(short* base, int d, int a2, float a, float b) {
    *reinterpret_cast<__hip_bfloat162*>(&base[d * KTLD + 2 * a2]) =
        __float22bfloat162_rn(make_float2(a, b));
}

// ---------------------------------------------------------------------------
// Phase 1 (v15): v14's bf16-MFMA structure at 4 blocks/CU.
//  v14 ledger: 56us, passed (absmax unchanged), MfmaUtil 1.6% / VALU 7.5% /
//  HBM 15% / Occ 16% — compute collapsed, pure exposed load latency at
//  2 blocks/CU (grid-limited split=8; LDS 41.98KB). HBM floor ~21us.
//  v15: (1) sKsumP eliminated — ksum partials live in sm.acc's dead pad
//  column 64 (written by a2==0 lanes inside the same sequential per-wave
//  reduce; deterministic). LDS 41984 -> 40960 = exactly 160KB/4.
//  (2) split=16 -> 1024 blocks = 4 resident blocks/CU (VGPR 100 < 128
//  permits 4 waves/SIMD). Per wave: 2 tiles of 32 s, same pinned regions.
//  Everything else identical to the passing v14.
// ---------------------------------------------------------------------------
__global__ __launch_bounds__(256, 2)
void la_phase1(const float* __restrict__ Kin, const float* __restrict__ Vin,
               float* __restrict__ partials, int split, int schunk)
{
    __shared__ union {
        struct { short Kt[4][64 * KTLD]; short Vt[4][64 * KTLD]; } st; // 40.96 KB
        float acc[64 * 68];                                            // 17.4 KB
    } sm;

    const int b     = blockIdx.x;
    const int nh    = b / split;
    const int chunk = b - nh * split;
    const int n     = nh >> 3;
    const int h     = nh & 7;
    const int s0    = chunk * schunk;

    const int tid  = threadIdx.x;
    const int w    = tid >> 6;
    const int lane = tid & 63;
    const int a2   = lane & 15;        // s-pair index (tile-local s = 2*a2, 2*a2+1)
    const int kg   = lane >> 4;        // k-group (0..3)
    const int dgrp = kg * 16;          // this lane stages d = dgrp..dgrp+15

    f32x4 acc[4][4];                   // 16 output tiles (m=d-tile, n=v-tile)
    f32x4 acck[4];                     // K_sum accumulator (A x ones)
    const f32x4 z4 = {0.f, 0.f, 0.f, 0.f};
    #pragma unroll
    for (int m = 0; m < 4; ++m) {
        acck[m] = z4;
        #pragma unroll
        for (int nn = 0; nn < 4; ++nn) acc[m][nn] = z4;
    }
    const bf16x8 ones = {0x3F80, 0x3F80, 0x3F80, 0x3F80,
                         0x3F80, 0x3F80, 0x3F80, 0x3F80};   // bf16 1.0 x8

    short* kt = sm.st.Kt[w];
    short* vt = sm.st.Vt[w];

    // per-lane global source pointers (advance by TSTEP per tile)
    const size_t base = (size_t)n * S_S * ROWF + h * D_D;
    const int swave   = s0 + w * (schunk >> 2) + 2 * a2;  // wave-private s-range
    const float* kpe = Kin + base + (size_t)swave * ROWF + dgrp;
    const float* kpo = kpe + ROWF;
    const float* vpe = Vin + base + (size_t)swave * ROWF + dgrp;
    const float* vpo = vpe + ROWF;

    const int ntiles = schunk >> 7;    // per-wave tiles of 32 s (2 at split=16)

    float4 kA0, kA1, kA2, kA3, kB0, kB1, kB2, kB3;
    float4 vA0, vA1, vA2, vA3, vB0, vB1, vB2, vB3;

#define LOADT()                                                              \
    do {                                                                     \
        kA0 = *(const float4*)(kpe + 0);  kA1 = *(const float4*)(kpe + 4);   \
        kA2 = *(const float4*)(kpe + 8);  kA3 = *(const float4*)(kpe + 12);  \
        kB0 = *(const float4*)(kpo + 0);  kB1 = *(const float4*)(kpo + 4);   \
        kB2 = *(const float4*)(kpo + 8);  kB3 = *(const float4*)(kpo + 12);  \
        vA0 = *(const float4*)(vpe + 0);  vA1 = *(const float4*)(vpe + 4);   \
        vA2 = *(const float4*)(vpe + 8);  vA3 = *(const float4*)(vpe + 12);  \
        vB0 = *(const float4*)(vpo + 0);  vB1 = *(const float4*)(vpo + 4);   \
        vB2 = *(const float4*)(vpo + 8);  vB3 = *(const float4*)(vpo + 12);  \
        kpe += TSTEP; kpo += TSTEP; vpe += TSTEP; vpo += TSTEP;              \
    } while (0)

#define WRITET()                                                             \
    do {                                                                     \
        wr_pair(kt, dgrp +  0, a2, elu1(kA0.x), elu1(kB0.x));                \
        wr_pair(kt, dgrp +  1, a2, elu1(kA0.y), elu1(kB0.y));                \
        wr_pair(kt, dgrp +  2, a2, elu1(kA0.z), elu1(kB0.z));                \
        wr_pair(kt, dgrp +  3, a2, elu1(kA0.w), elu1(kB0.w));                \
        wr_pair(kt, dgrp +  4, a2, elu1(kA1.x), elu1(kB1.x));                \
        wr_pair(kt, dgrp +  5, a2, elu1(kA1.y), elu1(kB1.y));                \
        wr_pair(kt, dgrp +  6, a2, elu1(kA1.z), elu1(kB1.z));                \
        wr_pair(kt, dgrp +  7, a2, elu1(kA1.w), elu1(kB1.w));                \
        wr_pair(kt, dgrp +  8, a2, elu1(kA2.x), elu1(kB2.x));                \
        wr_pair(kt, dgrp +  9, a2, elu1(kA2.y), elu1(kB2.y));                \
        wr_pair(kt, dgrp + 10, a2, elu1(kA2.z), elu1(kB2.z));                \
        wr_pair(kt, dgrp + 11, a2, elu1(kA2.w), elu1(kB2.w));                \
        wr_pair(kt, dgrp + 12, a2, elu1(kA3.x), elu1(kB3.x));                \
        wr_pair(kt, dgrp + 13, a2, elu1(kA3.y), elu1(kB3.y));                \
        wr_pair(kt, dgrp + 14, a2, elu1(kA3.z), elu1(kB3.z));                \
        wr_pair(kt, dgrp + 15, a2, elu1(kA3.w), elu1(kB3.w));                \
        wr_pair(vt, dgrp +  0, a2, vA0.x, vB0.x);                            \
        wr_pair(vt, dgrp +  1, a2, vA0.y, vB0.y);                            \
        wr_pair(vt, dgrp +  2, a2, vA0.z, vB0.z);                            \
        wr_pair(vt, dgrp +  3, a2, vA0.w, vB0.w);                            \
        wr_pair(vt, dgrp +  4, a2, vA1.x, vB1.x);                            \
        wr_pair(vt, dgrp +  5, a2, vA1.y, vB1.y);                            \
        wr_pair(vt, dgrp +  6, a2, vA1.z, vB1.z);                            \
        wr_pair(vt, dgrp +  7, a2, vA1.w, vB1.w);                            \
        wr_pair(vt, dgrp +  8, a2, vA2.x, vB2.x);                            \
        wr_pair(vt, dgrp +  9, a2, vA2.y, vB2.y);                            \
        wr_pair(vt, dgrp + 10, a2, vA2.z, vB2.z);                            \
        wr_pair(vt, dgrp + 11, a2, vA2.w, vB2.w);                            \
        wr_pair(vt, dgrp + 12, a2, vA3.x, vB3.x);                            \
        wr_pair(vt, dgrp + 13, a2, vA3.y, vB3.y);                            \
        wr_pair(vt, dgrp + 14, a2, vA3.z, vB3.z);                            \
        wr_pair(vt, dgrp + 15, a2, vA3.w, vB3.w);                            \
    } while (0)

    // ---- prologue: tile 0 staged ----
    LOADT();
    WRITET();

    for (int t = 0; t < ntiles; ++t) {
        const bool more = (t + 1 < ntiles);

        // region 1: issue tile t+1 into held regs
        if (more) LOADT();
        __builtin_amdgcn_sched_barrier(0);

        // region 2: MFMA compute on tile t (fragments from LDS)
        {
            // A-frag (K^T): row = m*16 + (lane&15) = d, k = kg*8.. (s)
            bf16x8 af0 = *(const bf16x8*)&kt[(0 * 16 + a2) * KTLD + kg * 8];
            bf16x8 af1 = *(const bf16x8*)&kt[(1 * 16 + a2) * KTLD + kg * 8];
            bf16x8 af2 = *(const bf16x8*)&kt[(2 * 16 + a2) * KTLD + kg * 8];
            bf16x8 af3 = *(const bf16x8*)&kt[(3 * 16 + a2) * KTLD + kg * 8];
            // B-frag (V): col = n*16 + (lane&15) = v, k = kg*8.. (s)
            bf16x8 bf0 = *(const bf16x8*)&vt[(0 * 16 + a2) * KTLD + kg * 8];
            bf16x8 bf1 = *(const bf16x8*)&vt[(1 * 16 + a2) * KTLD + kg * 8];
            bf16x8 bf2 = *(const bf16x8*)&vt[(2 * 16 + a2) * KTLD + kg * 8];
            bf16x8 bf3 = *(const bf16x8*)&vt[(3 * 16 + a2) * KTLD + kg * 8];

            acc[0][0] = __builtin_amdgcn_mfma_f32_16x16x32_bf16(af0, bf0, acc[0][0], 0, 0, 0);
            acc[0][1] = __builtin_amdgcn_mfma_f32_16x16x32_bf16(af0, bf1, acc[0][1], 0, 0, 0);
            acc[0][2] = __builtin_amdgcn_mfma_f32_16x16x32_bf16(af0, bf2, acc[0][2], 0, 0, 0);
            acc[0][3] = __builtin_amdgcn_mfma_f32_16x16x32_bf16(af0, bf3, acc[0][3], 0, 0, 0);
            acc[1][0] = __builtin_amdgcn_mfma_f32_16x16x32_bf16(af1, bf0, acc[1][0], 0, 0, 0);
            acc[1][1] = __builtin_amdgcn_mfma_f32_16x16x32_bf16(af1, bf1, acc[1][1], 0, 0, 0);
            acc[1][2] = __builtin_amdgcn_mfma_f32_16x16x32_bf16(af1, bf2, acc[1][2], 0, 0, 0);
            acc[1][3] = __builtin_amdgcn_mfma_f32_16x16x32_bf16(af1, bf3, acc[1][3], 0, 0, 0);
            acc[2][0] = __builtin_amdgcn_mfma_f32_16x16x32_bf16(af2, bf0, acc[2][0], 0, 0, 0);
            acc[2][1] = __builtin_amdgcn_mfma_f32_16x16x32_bf16(af2, bf1, acc[2][1], 0, 0, 0);
            acc[2][2] = __builtin_amdgcn_mfma_f32_16x16x32_bf16(af2, bf2, acc[2][2], 0, 0, 0);
            acc[2][3] = __builtin_amdgcn_mfma_f32_16x16x32_bf16(af2, bf3, acc[2][3], 0, 0, 0);
            acc[3][0] = __builtin_amdgcn_mfma_f32_16x16x32_bf16(af3, bf0, acc[3][0], 0, 0, 0);
            acc[3][1] = __builtin_amdgcn_mfma_f32_16x16x32_bf16(af3, bf1, acc[3][1], 0, 0, 0);
            acc[3][2] = __builtin_amdgcn_mfma_f32_16x16x32_bf16(af3, bf2, acc[3][2], 0, 0, 0);
            acc[3][3] = __builtin_amdgcn_mfma_f32_16x16x32_bf16(af3, bf3, acc[3][3], 0, 0, 0);
            // K_sum: A x ones -> row sums of K^T (all 16 cols identical)
            acck[0] = __builtin_amdgcn_mfma_f32_16x16x32_bf16(af0, ones, acck[0], 0, 0, 0);
            acck[1] = __builtin_amdgcn_mfma_f32_16x16x32_bf16(af1, ones, acck[1], 0, 0, 0);
            acck[2] = __builtin_amdgcn_mfma_f32_16x16x32_bf16(af2, ones, acck[2], 0, 0, 0);
            acck[3] = __builtin_amdgcn_mfma_f32_16x16x32_bf16(af3, ones, acck[3], 0, 0, 0);
        }
        __builtin_amdgcn_sched_barrier(0);

        // region 3: elu + cvt_pk + transposed store of tile t+1 (wave-private,
        // same buffer: this wave's compute(t) reads are already complete)
        if (more) WRITET();
    }
#undef LOADT
#undef WRITET

    __syncthreads();   // all waves done; sm.acc (union) safe to overwrite

    // cross-wave reduce of acc into sm.acc[d][v] (stride 68), sequential &
    // exact. C/D layout (m89-verified): col = lane&15, row = (lane>>4)*4+reg.
    // ksum partials ride in the dead pad column 64 (a2==0 lanes only).
    for (int ww = 0; ww < 4; ++ww) {
        if (w == ww) {
            #pragma unroll
            for (int m = 0; m < 4; ++m)
                #pragma unroll
                for (int nn = 0; nn < 4; ++nn)
                    #pragma unroll
                    for (int r = 0; r < 4; ++r) {
                        const int d = m * 16 + kg * 4 + r;
                        const int v = nn * 16 + a2;
                        if (ww == 0) sm.acc[d * 68 + v]  = acc[m][nn][r];
                        else         sm.acc[d * 68 + v] += acc[m][nn][r];
                    }
            if (a2 == 0) {
                #pragma unroll
                for (int m = 0; m < 4; ++m)
                    #pragma unroll
                    for (int r = 0; r < 4; ++r) {
                        const int d = m * 16 + kg * 4 + r;
                        if (ww == 0) sm.acc[d * 68 + 64]  = acck[m][r];
                        else         sm.acc[d * 68 + 64] += acck[m][r];
                    }
            }
        }
        __syncthreads();
    }

    // write this block's partial KV_aug[65][68] d-major (row 64 = K_sum, pads 0)
    float* outp = partials + (size_t)b * KVSZ;
    for (int idx = tid; idx < KVSZ; idx += 256) {
        const int r = idx / KVLD;
        const int c = idx - r * KVLD;
        float val = 0.f;
        if (c < 64) {
            if (r < 64)
                val = sm.acc[idx];          // [d][v] stride 68 == same layout
            else
                val = sm.acc[c * 68 + 64];  // ksum for d=c (pad col 64)
        }
        outp[idx] = val;
    }
}

// ---------------------------------------------------------------------------
// Reduce: sum the `split` partials per (n,h) -> kvt[nh][65][68]
// ---------------------------------------------------------------------------
__global__ __launch_bounds__(256)
void la_reduce(const float* __restrict__ partials, float* __restrict__ kvt, int split)
{
    const int idx = blockIdx.x * 256 + threadIdx.x;
    if (idx >= NH * KVSZ) return;
    const int nh  = idx / KVSZ;
    const int rem = idx - nh * KVSZ;
    const float* p = partials + (size_t)nh * split * KVSZ + rem;
    float s = 0.f;
    for (int c = 0; c < split; ++c) s += p[(size_t)c * KVSZ];
    kvt[idx] = s;
}

// ---------------------------------------------------------------------------
// Phase 2 (v5): register-tiled GEMM, Out[4096][65] = Qf[4096][64]*KV[64][65].
//  Per wave 64 rows x 32 cols, lane owns 8x4 tile; per k-chunk(4): 13
//  ds_read_b128 feed 160 FMAs; KV reused 8x, Q 4x in registers. Denominator
//  = KV row 64, accumulated per-lane for its own rows. Direct global stores.
//  (Round-6 measured ~20us ~= its 21us HBM floor -> unchanged.)
// ---------------------------------------------------------------------------
__global__ __launch_bounds__(256, 2)
void la_phase2(const float* __restrict__ Qin, const float* __restrict__ kvt,
               float* __restrict__ Out)
{
    __shared__ float sQ[128 * 68];   // 34.8 KB, row-major, stride 68
    __shared__ float sKV[KVSZ];      // 17.3 KB, [65][68] d-major

    const int b   = blockIdx.x;
    const int nh  = b >> 5;          // 32 l-chunks of 128 rows per (n,h)
    const int lc  = b & 31;
    const int n   = nh >> 3;
    const int h   = nh & 7;
    const int tid = threadIdx.x;
    const int w    = tid >> 6;
    const int lane = tid & 63;

    const float* Qc = Qin + (((size_t)n * L_L + (size_t)lc * 128) * H_H + h) * D_D;
    float*       Oc = Out + (((size_t)n * L_L + (size_t)lc * 128) * H_H + h) * D_D;

    // ---- stage KV_aug[65][68] into LDS (1105 float4, coalesced) ----
    {
        const float4* src = (const float4*)(kvt + (size_t)nh * KVSZ);
        float4*       dst = (float4*)sKV;
        #pragma unroll
        for (int it = 0; it < 4; ++it)
            dst[it * 256 + tid] = src[it * 256 + tid];
        if (tid < 81) dst[1024 + tid] = src[1024 + tid];
    }

    // ---- stage Q tile 128 rows x 64 cols (elu applied), stride 68 ----
    #pragma unroll
    for (int it = 0; it < 8; ++it) {
        const int slot = it * 256 + tid;   // 0..2047
        const int r    = slot >> 4;        // 0..127
        const int c4   = slot & 15;
        float4 v = *(const float4*)(Qc + (size_t)r * (H_H * D_D) + c4 * 4);
        v.x = elu1(v.x); v.y = elu1(v.y); v.z = elu1(v.z); v.w = elu1(v.w);
        *(float4*)&sQ[r * 68 + c4 * 4] = v;
    }
    __syncthreads();

    // ---- wave work assignment ----
    const int rt   = (w >> 1) * 64;        // row tile: 0 or 64
    const int wc   = w & 1;                // col half: 0 or 1
    const int rl   = lane & 7;             // row lane: rows rt + rl + 8j
    const int cg   = lane >> 3;            // col group
    const int ccol = wc * 32 + cg * 4;     // this lane's 4 output cols

    float acc[8][4];
    float den[8];
    #pragma unroll
    for (int j = 0; j < 8; ++j) {
        den[j] = 0.f;
        #pragma unroll
        for (int m = 0; m < 4; ++m) acc[j][m] = 0.f;
    }

    const int qbase = rt + rl;             // + 8j, stride-68 rows

    for (int kc = 0; kc < 16; ++kc) {
        // Q fragments: 8 rows x 4 k  (conflict-free b128: banks partition)
        float4 qv[8];
        #pragma unroll
        for (int j = 0; j < 8; ++j)
            qv[j] = *(const float4*)&sQ[(qbase + 8 * j) * 68 + kc * 4];
        // KV fragments: 4 k-rows x lane's 4 cols (conflict-free)
        const float4 kv0 = *(const float4*)&sKV[(kc * 4 + 0) * KVLD + ccol];
        const float4 kv1 = *(const float4*)&sKV[(kc * 4 + 1) * KVLD + ccol];
        const float4 kv2 = *(const float4*)&sKV[(kc * 4 + 2) * KVLD + ccol];
        const float4 kv3 = *(const float4*)&sKV[(kc * 4 + 3) * KVLD + ccol];
        // K_sum fragment: wave-uniform broadcast
        const float4 ks  = *(const float4*)&sKV[64 * KVLD + kc * 4];

        #pragma unroll
        for (int j = 0; j < 8; ++j) {
            const float q0 = qv[j].x, q1 = qv[j].y, q2 = qv[j].z, q3 = qv[j].w;
            den[j] = fmaf(q0, ks.x, den[j]);
            den[j] = fmaf(q1, ks.y, den[j]);
            den[j] = fmaf(q2, ks.z, den[j]);
            den[j] = fmaf(q3, ks.w, den[j]);
            acc[j][0] = fmaf(q0, kv0.x, acc[j][0]);
            acc[j][0] = fmaf(q1, kv1.x, acc[j][0]);
            acc[j][0] = fmaf(q2, kv2.x, acc[j][0]);
            acc[j][0] = fmaf(q3, kv3.x, acc[j][0]);
            acc[j][1] = fmaf(q0, kv0.y, acc[j][1]);
            acc[j][1] = fmaf(q1, kv1.y, acc[j][1]);
            acc[j][1] = fmaf(q2, kv2.y, acc[j][1]);
            acc[j][1] = fmaf(q3, kv3.y, acc[j][1]);
            acc[j][2] = fmaf(q0, kv0.z, acc[j][2]);
            acc[j][2] = fmaf(q1, kv1.z, acc[j][2]);
            acc[j][2] = fmaf(q2, kv2.z, acc[j][2]);
            acc[j][2] = fmaf(q3, kv3.z, acc[j][2]);
            acc[j][3] = fmaf(q0, kv0.w, acc[j][3]);
            acc[j][3] = fmaf(q1, kv1.w, acc[j][3]);
            acc[j][3] = fmaf(q2, kv2.w, acc[j][3]);
            acc[j][3] = fmaf(q3, kv3.w, acc[j][3]);
        }
    }

    // ---- epilogue: scale by 1/(den+eps), direct coalesced global stores ----
    #pragma unroll
    for (int j = 0; j < 8; ++j) {
        const float rz = 1.0f / (den[j] + 1e-6f);
        *(float4*)(Oc + (size_t)(qbase + 8 * j) * (H_H * D_D) + ccol) =
            make_float4(acc[j][0] * rz, acc[j][1] * rz,
                        acc[j][2] * rz, acc[j][3] * rz);
    }
}

// ---------------------------------------------------------------------------
extern "C" void kernel_launch(void* const* d_in, const int* in_sizes, int n_in,
                              void* d_out, int out_size, void* d_ws, size_t ws_size,
                              hipStream_t stream)
{
    const float* Q = (const float*)d_in[0];
    const float* K = (const float*)d_in[1];
    const float* V = (const float*)d_in[2];
    float* out = (float*)d_out;

    // ws layout: [ kvt: NH*KVSZ floats ][ partials: NH*split*KVSZ floats ]
    float* kvt = (float*)d_ws;
    const size_t kvt_bytes = (size_t)NH * KVSZ * sizeof(float);

    int split = 16;   // 1024 blocks = 4 resident blocks/CU at 40960B LDS
    while (split > 1 &&
           kvt_bytes + (size_t)NH * split * KVSZ * sizeof(float) > ws_size)
        split >>= 1;
    float* partials = kvt + (size_t)NH * KVSZ;
    const int schunk = S_S / split;

    la_phase1<<<NH * split, 256, 0, stream>>>(K, V, partials, split, schunk);

    const int red_blocks = (NH * KVSZ + 255) / 256;   // 1105 exactly
    la_reduce<<<red_blocks, 256, 0, stream>>>(partials, kvt, split);

    la_phase2<<<NH * (L_L / 128), 256, 0, stream>>>(Q, kvt, out);
}

// Round 21
// 83.734 us; speedup vs baseline: 1.1004x; 1.1004x over previous
//
#include <hip/hip_runtime.h>
#include <hip/hip_bf16.h>
#include <cstddef>
#include <cstdint>

// Problem constants (fixed by the reference setup)
#define N_B   8
#define L_L   4096
#define S_S   4096
#define H_H   8
#define D_D   64
#define NH    64          // N_B * H_H
// KV_aug layout (d-major): rows 0..63 = KV[d][v] (stride 68, cols 64..67 pad),
// row 64 = K_sum[d] (indexed by d in cols 0..63). KVSZ floats per (n,h).
#define KVLD  68
#define KVSZ  (65 * KVLD)   // 4420
#define ROWF  (H_H * D_D)   // 512 floats per s-row
#define TSTEP (32 * ROWF)   // floats per 32-s tile step
#define KTLD  40            // bf16 (short) row stride of transposed tiles (80 B)

typedef float f32x4 __attribute__((ext_vector_type(4)));
typedef short bf16x8 __attribute__((ext_vector_type(8)));

__device__ __forceinline__ float elu1(float x) {
    // elu(x)+1 : x>0 ? x+1 : exp(x)
    return x > 0.f ? x + 1.f : __expf(x);
}

// pack (a,b) -> bf16x2 (RNE), store transposed at [d][2p..2p+1]
__device__ __forceinline__ void wr_pair(short* base, int d, int p, float a, float b) {
    *reinterpret_cast<__hip_bfloat162*>(&base[d * KTLD + 2 * p]) =
        __float22bfloat162_rn(make_float2(a, b));
}

// ---------------------------------------------------------------------------
// Phase 1 (v16): cooperative-staged bf16 MFMA, d-slab wave split.
//  v14/v15 ledger: wave-private staging = uncoalesced 16B-granule loads, ~16
//  outstanding/wave -> Little's law caps at ~1.5TB/s (57us), MfmaUtil 1.6%.
//  The barrier-free rationale died when MFMA made compute negligible.
//  v16: block cooperatively stages one 32-s tile, COALESCED (16 consecutive
//  threads read 256B contiguous; thread owns s-rows 2p,2p+1 so the bf16x2
//  transposed write stays: 8 ds_write_b32/thread/tile). Output 64x64 splits
//  by d-slab across waves (wave w: d=w*16..+15): per tile/wave = 1 A-read +
//  4 B-reads + 5 MFMAs, and NO cross-wave reduce. One barrier/tile,
//  double-buffered LDS (20.5KB union'd with acc). Loads(t+1) issued before
//  compute(t). split=16 -> 1024 blocks = 4/CU. ~70 regs -> (256,4) safe.
// ---------------------------------------------------------------------------
__global__ __launch_bounds__(256, 4)
void la_phase1(const float* __restrict__ Kin, const float* __restrict__ Vin,
               float* __restrict__ partials, int split, int schunk)
{
    __shared__ union {
        struct { short Kt[2][64 * KTLD]; short Vt[2][64 * KTLD]; } st; // 20.5 KB
        float acc[64 * 68];                                            // 17.4 KB
    } sm;

    const int b     = blockIdx.x;
    const int nh    = b / split;
    const int chunk = b - nh * split;
    const int n     = nh >> 3;
    const int h     = nh & 7;
    const int s0    = chunk * schunk;

    const int tid  = threadIdx.x;
    const int w    = tid >> 6;
    const int lane = tid & 63;
    const int a2   = lane & 15;        // MFMA fragment col/row lane index
    const int kg   = lane >> 4;        // k-group (0..3)

    // staging map: thread -> s-row pair (2p, 2p+1), float cols c4..c4+3
    const int p  = tid >> 4;           // 0..15
    const int c4 = (tid & 15) * 4;     // 0,4,...,60

    f32x4 acc[4];                      // wave slab w x 4 v-tiles
    f32x4 acck;                        // K_sum (A x ones)
    const f32x4 z4 = {0.f, 0.f, 0.f, 0.f};
    acck = z4;
    #pragma unroll
    for (int nn = 0; nn < 4; ++nn) acc[nn] = z4;
    const bf16x8 ones = {0x3F80, 0x3F80, 0x3F80, 0x3F80,
                         0x3F80, 0x3F80, 0x3F80, 0x3F80};   // bf16 1.0 x8

    // per-thread global source pointers (advance by TSTEP per tile)
    const size_t base = (size_t)n * S_S * ROWF + h * D_D;
    const float* kpe = Kin + base + (size_t)(s0 + 2 * p) * ROWF + c4;
    const float* kpo = kpe + ROWF;
    const float* vpe = Vin + base + (size_t)(s0 + 2 * p) * ROWF + c4;
    const float* vpo = vpe + ROWF;

    const int ntiles = schunk >> 5;    // tiles of 32 s (8 at split=16)

    float4 ka, kb, va, vb;

#define LOADT()                                                              \
    do {                                                                     \
        ka = *(const float4*)kpe;  kb = *(const float4*)kpo;                 \
        va = *(const float4*)vpe;  vb = *(const float4*)vpo;                 \
        kpe += TSTEP; kpo += TSTEP; vpe += TSTEP; vpo += TSTEP;              \
    } while (0)

#define WRITET(BUF)                                                          \
    do {                                                                     \
        short* kt_ = sm.st.Kt[BUF];  short* vt_ = sm.st.Vt[BUF];             \
        wr_pair(kt_, c4 + 0, p, elu1(ka.x), elu1(kb.x));                     \
        wr_pair(kt_, c4 + 1, p, elu1(ka.y), elu1(kb.y));                     \
        wr_pair(kt_, c4 + 2, p, elu1(ka.z), elu1(kb.z));                     \
        wr_pair(kt_, c4 + 3, p, elu1(ka.w), elu1(kb.w));                     \
        wr_pair(vt_, c4 + 0, p, va.x, vb.x);                                 \
        wr_pair(vt_, c4 + 1, p, va.y, vb.y);                                 \
        wr_pair(vt_, c4 + 2, p, va.z, vb.z);                                 \
        wr_pair(vt_, c4 + 3, p, va.w, vb.w);                                 \
    } while (0)

    // ---- prologue: stage tile 0 into buf 0 ----
    LOADT();
    WRITET(0);
    __syncthreads();

    for (int t = 0; t < ntiles; ++t) {
        const bool more = (t + 1 < ntiles);

        if (more) LOADT();             // tile t+1 into held regs (16)

        // compute tile t: wave w owns d-slab w*16..w*16+15
        {
            const short* kt = sm.st.Kt[t & 1];
            const short* vt = sm.st.Vt[t & 1];
            const bf16x8 af = *(const bf16x8*)&kt[(w * 16 + a2) * KTLD + kg * 8];
            const bf16x8 b0 = *(const bf16x8*)&vt[(0 * 16 + a2) * KTLD + kg * 8];
            const bf16x8 b1 = *(const bf16x8*)&vt[(1 * 16 + a2) * KTLD + kg * 8];
            const bf16x8 b2 = *(const bf16x8*)&vt[(2 * 16 + a2) * KTLD + kg * 8];
            const bf16x8 b3 = *(const bf16x8*)&vt[(3 * 16 + a2) * KTLD + kg * 8];
            acc[0] = __builtin_amdgcn_mfma_f32_16x16x32_bf16(af, b0, acc[0], 0, 0, 0);
            acc[1] = __builtin_amdgcn_mfma_f32_16x16x32_bf16(af, b1, acc[1], 0, 0, 0);
            acc[2] = __builtin_amdgcn_mfma_f32_16x16x32_bf16(af, b2, acc[2], 0, 0, 0);
            acc[3] = __builtin_amdgcn_mfma_f32_16x16x32_bf16(af, b3, acc[3], 0, 0, 0);
            acck   = __builtin_amdgcn_mfma_f32_16x16x32_bf16(af, ones, acck, 0, 0, 0);
        }

        if (more) WRITET((t + 1) & 1); // compiler waitcnt covers the loads
        __syncthreads();               // writes visible; all waves past compute
    }
#undef LOADT
#undef WRITET

    // epilogue: slabs are disjoint -> direct writes into sm.acc (union safe:
    // final loop barrier followed the last compute).
    // C layout (m89): col = a2 -> v = nn*16+a2; row = kg*4+r -> d = w*16+kg*4+r
    #pragma unroll
    for (int nn = 0; nn < 4; ++nn)
        #pragma unroll
        for (int r = 0; r < 4; ++r)
            sm.acc[(w * 16 + kg * 4 + r) * 68 + nn * 16 + a2] = acc[nn][r];
    if (a2 == 0) {
        #pragma unroll
        for (int r = 0; r < 4; ++r)
            sm.acc[(w * 16 + kg * 4 + r) * 68 + 64] = acck[r];
    }
    __syncthreads();

    // write this block's partial KV_aug[65][68] d-major (row 64 = K_sum, pads 0)
    float* outp = partials + (size_t)b * KVSZ;
    for (int idx = tid; idx < KVSZ; idx += 256) {
        const int r = idx / KVLD;
        const int c = idx - r * KVLD;
        float val = 0.f;
        if (c < 64) {
            if (r < 64)
                val = sm.acc[idx];          // [d][v] stride 68 == same layout
            else
                val = sm.acc[c * 68 + 64];  // ksum for d=c (pad col 64)
        }
        outp[idx] = val;
    }
}

// ---------------------------------------------------------------------------
// Reduce: sum the `split` partials per (n,h) -> kvt[nh][65][68]
// ---------------------------------------------------------------------------
__global__ __launch_bounds__(256)
void la_reduce(const float* __restrict__ partials, float* __restrict__ kvt, int split)
{
    const int idx = blockIdx.x * 256 + threadIdx.x;
    if (idx >= NH * KVSZ) return;
    const int nh  = idx / KVSZ;
    const int rem = idx - nh * KVSZ;
    const float* p = partials + (size_t)nh * split * KVSZ + rem;
    float s = 0.f;
    for (int c = 0; c < split; ++c) s += p[(size_t)c * KVSZ];
    kvt[idx] = s;
}

// ---------------------------------------------------------------------------
// Phase 2 (v5): register-tiled GEMM, Out[4096][65] = Qf[4096][64]*KV[64][65].
//  Per wave 64 rows x 32 cols, lane owns 8x4 tile; per k-chunk(4): 13
//  ds_read_b128 feed 160 FMAs; KV reused 8x, Q 4x in registers. Denominator
//  = KV row 64, accumulated per-lane for its own rows. Direct global stores.
//  (Round-6 measured ~20us ~= its 21us HBM floor -> unchanged.)
// ---------------------------------------------------------------------------
__global__ __launch_bounds__(256, 2)
void la_phase2(const float* __restrict__ Qin, const float* __restrict__ kvt,
               float* __restrict__ Out)
{
    __shared__ float sQ[128 * 68];   // 34.8 KB, row-major, stride 68
    __shared__ float sKV[KVSZ];      // 17.3 KB, [65][68] d-major

    const int b   = blockIdx.x;
    const int nh  = b >> 5;          // 32 l-chunks of 128 rows per (n,h)
    const int lc  = b & 31;
    const int n   = nh >> 3;
    const int h   = nh & 7;
    const int tid = threadIdx.x;
    const int w    = tid >> 6;
    const int lane = tid & 63;

    const float* Qc = Qin + (((size_t)n * L_L + (size_t)lc * 128) * H_H + h) * D_D;
    float*       Oc = Out + (((size_t)n * L_L + (size_t)lc * 128) * H_H + h) * D_D;

    // ---- stage KV_aug[65][68] into LDS (1105 float4, coalesced) ----
    {
        const float4* src = (const float4*)(kvt + (size_t)nh * KVSZ);
        float4*       dst = (float4*)sKV;
        #pragma unroll
        for (int it = 0; it < 4; ++it)
            dst[it * 256 + tid] = src[it * 256 + tid];
        if (tid < 81) dst[1024 + tid] = src[1024 + tid];
    }

    // ---- stage Q tile 128 rows x 64 cols (elu applied), stride 68 ----
    #pragma unroll
    for (int it = 0; it < 8; ++it) {
        const int slot = it * 256 + tid;   // 0..2047
        const int r    = slot >> 4;        // 0..127
        const int c4   = slot & 15;
        float4 v = *(const float4*)(Qc + (size_t)r * (H_H * D_D) + c4 * 4);
        v.x = elu1(v.x); v.y = elu1(v.y); v.z = elu1(v.z); v.w = elu1(v.w);
        *(float4*)&sQ[r * 68 + c4 * 4] = v;
    }
    __syncthreads();

    // ---- wave work assignment ----
    const int rt   = (w >> 1) * 64;        // row tile: 0 or 64
    const int wc   = w & 1;                // col half: 0 or 1
    const int rl   = lane & 7;             // row lane: rows rt + rl + 8j
    const int cg   = lane >> 3;            // col group
    const int ccol = wc * 32 + cg * 4;     // this lane's 4 output cols

    float acc[8][4];
    float den[8];
    #pragma unroll
    for (int j = 0; j < 8; ++j) {
        den[j] = 0.f;
        #pragma unroll
        for (int m = 0; m < 4; ++m) acc[j][m] = 0.f;
    }

    const int qbase = rt + rl;             // + 8j, stride-68 rows

    for (int kc = 0; kc < 16; ++kc) {
        // Q fragments: 8 rows x 4 k  (conflict-free b128: banks partition)
        float4 qv[8];
        #pragma unroll
        for (int j = 0; j < 8; ++j)
            qv[j] = *(const float4*)&sQ[(qbase + 8 * j) * 68 + kc * 4];
        // KV fragments: 4 k-rows x lane's 4 cols (conflict-free)
        const float4 kv0 = *(const float4*)&sKV[(kc * 4 + 0) * KVLD + ccol];
        const float4 kv1 = *(const float4*)&sKV[(kc * 4 + 1) * KVLD + ccol];
        const float4 kv2 = *(const float4*)&sKV[(kc * 4 + 2) * KVLD + ccol];
        const float4 kv3 = *(const float4*)&sKV[(kc * 4 + 3) * KVLD + ccol];
        // K_sum fragment: wave-uniform broadcast
        const float4 ks  = *(const float4*)&sKV[64 * KVLD + kc * 4];

        #pragma unroll
        for (int j = 0; j < 8; ++j) {
            const float q0 = qv[j].x, q1 = qv[j].y, q2 = qv[j].z, q3 = qv[j].w;
            den[j] = fmaf(q0, ks.x, den[j]);
            den[j] = fmaf(q1, ks.y, den[j]);
            den[j] = fmaf(q2, ks.z, den[j]);
            den[j] = fmaf(q3, ks.w, den[j]);
            acc[j][0] = fmaf(q0, kv0.x, acc[j][0]);
            acc[j][0] = fmaf(q1, kv1.x, acc[j][0]);
            acc[j][0] = fmaf(q2, kv2.x, acc[j][0]);
            acc[j][0] = fmaf(q3, kv3.x, acc[j][0]);
            acc[j][1] = fmaf(q0, kv0.y, acc[j][1]);
            acc[j][1] = fmaf(q1, kv1.y, acc[j][1]);
            acc[j][1] = fmaf(q2, kv2.y, acc[j][1]);
            acc[j][1] = fmaf(q3, kv3.y, acc[j][1]);
            acc[j][2] = fmaf(q0, kv0.z, acc[j][2]);
            acc[j][2] = fmaf(q1, kv1.z, acc[j][2]);
            acc[j][2] = fmaf(q2, kv2.z, acc[j][2]);
            acc[j][2] = fmaf(q3, kv3.z, acc[j][2]);
            acc[j][3] = fmaf(q0, kv0.w, acc[j][3]);
            acc[j][3] = fmaf(q1, kv1.w, acc[j][3]);
            acc[j][3] = fmaf(q2, kv2.w, acc[j][3]);
            acc[j][3] = fmaf(q3, kv3.w, acc[j][3]);
        }
    }

    // ---- epilogue: scale by 1/(den+eps), direct coalesced global stores ----
    #pragma unroll
    for (int j = 0; j < 8; ++j) {
        const float rz = 1.0f / (den[j] + 1e-6f);
        *(float4*)(Oc + (size_t)(qbase + 8 * j) * (H_H * D_D) + ccol) =
            make_float4(acc[j][0] * rz, acc[j][1] * rz,
                        acc[j][2] * rz, acc[j][3] * rz);
    }
}

// ---------------------------------------------------------------------------
extern "C" void kernel_launch(void* const* d_in, const int* in_sizes, int n_in,
                              void* d_out, int out_size, void* d_ws, size_t ws_size,
                              hipStream_t stream)
{
    const float* Q = (const float*)d_in[0];
    const float* K = (const float*)d_in[1];
    const float* V = (const float*)d_in[2];
    float* out = (float*)d_out;

    // ws layout: [ kvt: NH*KVSZ floats ][ partials: NH*split*KVSZ floats ]
    float* kvt = (float*)d_ws;
    const size_t kvt_bytes = (size_t)NH * KVSZ * sizeof(float);

    int split = 16;   // 1024 blocks = 4 resident blocks/CU (LDS 20.5KB)
    while (split > 1 &&
           kvt_bytes + (size_t)NH * split * KVSZ * sizeof(float) > ws_size)
        split >>= 1;
    float* partials = kvt + (size_t)NH * KVSZ;
    const int schunk = S_S / split;

    la_phase1<<<NH * split, 256, 0, stream>>>(K, V, partials, split, schunk);

    const int red_blocks = (NH * KVSZ + 255) / 256;   // 1105 exactly
    la_reduce<<<red_blocks, 256, 0, stream>>>(partials, kvt, split);

    la_phase2<<<NH * (L_L / 128), 256, 0, stream>>>(Q, kvt, out);
}